// Round 3
// baseline (421.920 us; speedup 1.0000x reference)
//
#include <hip/hip_runtime.h>
#include <hip/hip_bf16.h>

#define N_NODES 20000
#define N_EDGES 640000
#define NRELS 20

typedef __attribute__((ext_vector_type(8))) short short8;
typedef __attribute__((ext_vector_type(8))) unsigned short ushort8;
typedef __attribute__((ext_vector_type(4))) float floatx4;
typedef unsigned short u16;
typedef unsigned int u32;

__device__ __forceinline__ float bf2f(u16 u){
  union { u32 i; float f; } v; v.i = ((u32)u) << 16; return v.f;
}
__device__ __forceinline__ u16 f2bf(float f){
  __hip_bfloat16 b = __float2bfloat16(f);
  return __builtin_bit_cast(u16, b);
}

// ---------------- K0: cast h (f32) -> hb (bf16) ------------------------------
__global__ void k_cast(const float* __restrict__ h, u16* __restrict__ hb){
  int i = (blockIdx.x * 256 + threadIdx.x) * 4;   // 2,560,000 / 4 = 640,000 thr
  float4 v = *(const float4*)(h + i);
  u16 o[4] = { f2bf(v.x), f2bf(v.y), f2bf(v.z), f2bf(v.w) };
  *(ushort4*)(hb + i) = *(ushort4*)o;
}

// ---------------- K1: w_relT[r][o][i] (bf16), reference reshape semantics ----
// w_rel[r][i][o]: with q = r*128+i: value = sum_b w_comp[q%20][b]*weight[(q/20)*1024+b*128+o]
__global__ void k_wrel(const float* __restrict__ weight, const float* __restrict__ w_comp,
                       u16* __restrict__ wrelT){
  int f = blockIdx.x * 256 + threadIdx.x;
  if (f >= NRELS * 128 * 128) return;
  int i  = f & 127;
  int ro = f >> 7;
  int o  = ro & 127;
  int r  = ro >> 7;
  int q  = r * 128 + i;
  int rr = q % 20, ii = q / 20;
  float acc = 0.f;
  #pragma unroll
  for (int b = 0; b < 8; ++b)
    acc += w_comp[rr * 8 + b] * weight[ii * 1024 + b * 128 + o];
  wrelT[f] = f2bf(acc);          // layout [r][o][i] -> GEMM stages B^T coalesced
}

// ---------------- K2: xW[r][n][o] = h @ W_r via MFMA bf16 --------------------
// BM=64 tile: static LDS = (64+128)*136*2 = 52224 B  (< 64 KiB)
#define LDP 136   // 128 + 8 pad: 272B pitch, 16B-aligned, 2-way-max banks

template<bool XW_F32>
__global__ __launch_bounds__(256, 2) void k_gemm(
    const u16* __restrict__ hb, const u16* __restrict__ wrelT, void* __restrict__ xWv){
  __shared__ u16 smem[(64 + 128) * LDP];
  u16* As = smem;                // [64][136]   A[m][k]
  u16* Bs = smem + 64 * LDP;     // [128][136]  Bs[n][k] (transposed B)
  const int r   = blockIdx.y;
  const int m0  = blockIdx.x * 64;
  const int tid = threadIdx.x;
  const int trow = tid >> 4;          // 0..15
  const int tcol = (tid & 15) * 8;    // 0..120 step 8
  const int4 zero4 = make_int4(0, 0, 0, 0);
  #pragma unroll
  for (int it = 0; it < 4; ++it){
    int rl = trow + it * 16;          // 0..63
    int gr = m0 + rl;
    int4 a = (gr < N_NODES) ? *(const int4*)(hb + (size_t)gr * 128 + tcol) : zero4;
    *(int4*)(As + rl * LDP + tcol) = a;
  }
  #pragma unroll
  for (int it = 0; it < 8; ++it){
    int rl = trow + it * 16;          // 0..127
    int4 b = *(const int4*)(wrelT + ((size_t)r * 128 + rl) * 128 + tcol);
    *(int4*)(Bs + rl * LDP + tcol) = b;
  }
  __syncthreads();
  const int wave = tid >> 6, lane = tid & 63;
  const int lrow = lane & 15;
  const int lk   = (lane >> 4) * 8;
  floatx4 acc[8] = {};
  #pragma unroll
  for (int ks = 0; ks < 4; ++ks){
    short8 a0 = *(const short8*)(As + (wave * 16 + lrow) * LDP + ks * 32 + lk);
    #pragma unroll
    for (int nf = 0; nf < 8; ++nf){
      short8 b = *(const short8*)(Bs + (nf * 16 + lrow) * LDP + ks * 32 + lk);
      acc[nf] = __builtin_amdgcn_mfma_f32_16x16x32_bf16(a0, b, acc[nf], 0, 0, 0);
    }
  }
  __syncthreads();
  // epilogue: transpose through LDS (f32 [64][132] = 33792 B, reuses smem)
  float* Cs = (float*)smem;
  #pragma unroll
  for (int nf = 0; nf < 8; ++nf)
  #pragma unroll
  for (int j = 0; j < 4; ++j){
    int row = wave * 16 + ((lane >> 4) << 2) + j;  // C/D: row=(l>>4)*4+reg
    int col = nf * 16 + (lane & 15);               //      col=l&15
    Cs[row * 132 + col] = acc[nf][j];
  }
  __syncthreads();
  const size_t obase = ((size_t)r * N_NODES + m0) * 128;
  #pragma unroll
  for (int it = 0; it < 4; ++it){
    int row = trow + it * 16;         // 0..63
    if (m0 + row < N_NODES){
      const float* p = Cs + row * 132 + tcol;
      if (XW_F32){
        float* xW = (float*)xWv;
        *(float4*)(xW + obase + (size_t)row * 128 + tcol)     = *(const float4*)(p);
        *(float4*)(xW + obase + (size_t)row * 128 + tcol + 4) = *(const float4*)(p + 4);
      } else {
        u16* xW = (u16*)xWv;
        ushort8 u;
        #pragma unroll
        for (int k = 0; k < 8; ++k) u[k] = f2bf(p[k]);
        *(ushort8*)(xW + obase + (size_t)row * 128 + tcol) = u;
      }
    }
  }
}

// ---------------- K3: CSR build over dst -------------------------------------
__global__ void k_count(const int* __restrict__ dst, int* __restrict__ counts){
  int e = blockIdx.x * 256 + threadIdx.x;
  if (e < N_EDGES) atomicAdd(&counts[dst[e]], 1);
}

__global__ __launch_bounds__(256) void k_scan(const int* __restrict__ counts,
    int* __restrict__ offsets, int* __restrict__ cursor){
  __shared__ int sums[256];
  const int t = threadIdx.x;
  const int CH = 80;                  // 256*80 = 20480 >= 20000
  const int base = t * CH;
  int s = 0;
  for (int j = 0; j < CH; ++j){
    int idx = base + j;
    if (idx < N_NODES) s += counts[idx];
  }
  sums[t] = s;
  __syncthreads();
  for (int off = 1; off < 256; off <<= 1){
    int v = (t >= off) ? sums[t - off] : 0;
    __syncthreads();
    sums[t] += v;
    __syncthreads();
  }
  int run = (t == 0) ? 0 : sums[t - 1];
  for (int j = 0; j < CH; ++j){
    int idx = base + j;
    if (idx < N_NODES){
      int c = counts[idx];
      offsets[idx] = run; cursor[idx] = run; run += c;
    }
  }
  if (t == 255) offsets[N_NODES] = sums[255];   // = 640000
}

__global__ void k_fill(const int* __restrict__ dst, int* __restrict__ cursor,
                       int* __restrict__ eids){
  int e = blockIdx.x * 256 + threadIdx.x;
  if (e < N_EDGES){
    int p = atomicAdd(&cursor[dst[e]], 1);
    eids[p] = e;
  }
}

// ---------------- K4: gather + segment-sum + relu ----------------------------
template<bool XW_F32>
__global__ __launch_bounds__(128) void k_agg(const int* __restrict__ offsets,
    const int* __restrict__ eids, const int* __restrict__ src,
    const int* __restrict__ ety, const void* __restrict__ xWv, float* __restrict__ out){
  const int n = blockIdx.x;
  const int t = threadIdx.x;
  float acc = 0.f;
  const int b0 = offsets[n], b1 = offsets[n + 1];
  for (int e = b0; e < b1; ++e){
    int id = eids[e];
    int s  = src[id];
    int rr = ety[id];
    size_t off = ((size_t)rr * N_NODES + s) * 128 + t;
    if (XW_F32) acc += ((const float*)xWv)[off];
    else        acc += bf2f(((const u16*)xWv)[off]);
  }
  out[(size_t)n * 128 + t] = fmaxf(acc, 0.f);
}

// ---------------- launcher ---------------------------------------------------
extern "C" void kernel_launch(void* const* d_in, const int* in_sizes, int n_in,
                              void* d_out, int out_size, void* d_ws, size_t ws_size,
                              hipStream_t stream){
  const float* h      = (const float*)d_in[0];
  const float* weight = (const float*)d_in[1];
  const float* w_comp = (const float*)d_in[2];
  const int* src      = (const int*)d_in[3];
  const int* dst      = (const int*)d_in[4];
  const int* etype    = (const int*)d_in[5];
  float* out = (float*)d_out;

  const bool xw_f32 = (ws_size >= 215000000ull);
  char* p = (char*)d_ws;
  void* xW  = (void*)p;                 p += xw_f32 ? 204800000 : 102400000;
  u16* hb     = (u16*)p;                p += 5120000;
  u16* wrelT  = (u16*)p;                p += 655360;
  int* counts = (int*)p;                p += 80000;
  int* offs   = (int*)p;                p += 80128;
  int* cursor = (int*)p;                p += 80000;
  int* eids   = (int*)p;                /* 2,560,000 B */

  hipMemsetAsync(counts, 0, N_NODES * sizeof(int), stream);
  k_cast <<<dim3(2500), dim3(256), 0, stream>>>(h, hb);
  k_wrel <<<dim3((NRELS * 128 * 128 + 255) / 256), dim3(256), 0, stream>>>(weight, w_comp, wrelT);
  k_count<<<dim3(N_EDGES / 256), dim3(256), 0, stream>>>(dst, counts);
  k_scan <<<dim3(1), dim3(256), 0, stream>>>(counts, offs, cursor);
  k_fill <<<dim3(N_EDGES / 256), dim3(256), 0, stream>>>(dst, cursor, eids);
  if (xw_f32){
    k_gemm<true> <<<dim3(313, NRELS), dim3(256), 0, stream>>>(hb, wrelT, xW);
    k_agg<true>  <<<dim3(N_NODES), dim3(128), 0, stream>>>(offs, eids, src, etype, xW, out);
  } else {
    k_gemm<false><<<dim3(313, NRELS), dim3(256), 0, stream>>>(hb, wrelT, xW);
    k_agg<false> <<<dim3(N_NODES), dim3(128), 0, stream>>>(offs, eids, src, etype, xW, out);
  }
}

// Round 4
// 214.335 us; speedup vs baseline: 1.9685x; 1.9685x over previous
//
#include <hip/hip_runtime.h>
#include <hip/hip_bf16.h>

#define N_NODES 20000
#define N_EDGES 640000
#define NRELS 20
#define NB_SCAN 79   // ceil(20000/256)

typedef __attribute__((ext_vector_type(8))) short short8;
typedef __attribute__((ext_vector_type(8))) unsigned short ushort8;
typedef __attribute__((ext_vector_type(4))) float floatx4;
typedef unsigned short u16;
typedef unsigned int u32;

__device__ __forceinline__ float bf2f(u16 u){
  union { u32 i; float f; } v; v.i = ((u32)u) << 16; return v.f;
}
__device__ __forceinline__ u16 f2bf(float f){
  __hip_bfloat16 b = __float2bfloat16(f);
  return __builtin_bit_cast(u16, b);
}

// ---------------- K0: cast h -> bf16, and count dst degrees (same grid) ------
__global__ void k_cast_count(const float* __restrict__ h, u16* __restrict__ hb,
                             const int* __restrict__ dst, int* __restrict__ counts){
  int tidg = blockIdx.x * 256 + threadIdx.x;       // 640,000 threads
  int i = tidg * 4;
  float4 v = *(const float4*)(h + i);
  u16 o[4] = { f2bf(v.x), f2bf(v.y), f2bf(v.z), f2bf(v.w) };
  *(ushort4*)(hb + i) = *(ushort4*)o;
  atomicAdd(&counts[dst[tidg]], 1);
}

// ---------------- K1: w_relT[r][o][i] (bf16), reference reshape semantics ----
__global__ void k_wrel(const float* __restrict__ weight, const float* __restrict__ w_comp,
                       u16* __restrict__ wrelT){
  int f = blockIdx.x * 256 + threadIdx.x;
  if (f >= NRELS * 128 * 128) return;
  int i  = f & 127;
  int ro = f >> 7;
  int o  = ro & 127;
  int r  = ro >> 7;
  int q  = r * 128 + i;
  int rr = q % 20, ii = q / 20;
  float acc = 0.f;
  #pragma unroll
  for (int b = 0; b < 8; ++b)
    acc += w_comp[rr * 8 + b] * weight[ii * 1024 + b * 128 + o];
  wrelT[f] = f2bf(acc);          // [r][o][i] -> GEMM stages B^T coalesced
}

// ---------------- K2: xW[r][n][o] = h @ W_r via MFMA bf16, bf16 out ----------
#define LDP 136   // 128 + 8 pad: 272B pitch, 16B-aligned, 2-way-max banks

__global__ __launch_bounds__(256, 2) void k_gemm(
    const u16* __restrict__ hb, const u16* __restrict__ wrelT, u16* __restrict__ xW){
  __shared__ u16 smem[(64 + 128) * LDP];   // 52224 B
  u16* As = smem;                // [64][136]
  u16* Bs = smem + 64 * LDP;     // [128][136]  Bs[n][k]
  const int r   = blockIdx.y;
  const int m0  = blockIdx.x * 64;
  const int tid = threadIdx.x;
  const int trow = tid >> 4;
  const int tcol = (tid & 15) * 8;
  const int4 zero4 = make_int4(0, 0, 0, 0);
  #pragma unroll
  for (int it = 0; it < 4; ++it){
    int rl = trow + it * 16;
    int gr = m0 + rl;
    int4 a = (gr < N_NODES) ? *(const int4*)(hb + (size_t)gr * 128 + tcol) : zero4;
    *(int4*)(As + rl * LDP + tcol) = a;
  }
  #pragma unroll
  for (int it = 0; it < 8; ++it){
    int rl = trow + it * 16;
    int4 b = *(const int4*)(wrelT + ((size_t)r * 128 + rl) * 128 + tcol);
    *(int4*)(Bs + rl * LDP + tcol) = b;
  }
  __syncthreads();
  const int wave = tid >> 6, lane = tid & 63;
  const int lrow = lane & 15;
  const int lk   = (lane >> 4) * 8;
  floatx4 acc[8] = {};
  #pragma unroll
  for (int ks = 0; ks < 4; ++ks){
    short8 a0 = *(const short8*)(As + (wave * 16 + lrow) * LDP + ks * 32 + lk);
    #pragma unroll
    for (int nf = 0; nf < 8; ++nf){
      short8 b = *(const short8*)(Bs + (nf * 16 + lrow) * LDP + ks * 32 + lk);
      acc[nf] = __builtin_amdgcn_mfma_f32_16x16x32_bf16(a0, b, acc[nf], 0, 0, 0);
    }
  }
  __syncthreads();
  float* Cs = (float*)smem;      // [64][132] f32 = 33792 B
  #pragma unroll
  for (int nf = 0; nf < 8; ++nf)
  #pragma unroll
  for (int j = 0; j < 4; ++j){
    int row = wave * 16 + ((lane >> 4) << 2) + j;  // C/D: row=(l>>4)*4+reg
    int col = nf * 16 + (lane & 15);               //      col=l&15
    Cs[row * 132 + col] = acc[nf][j];
  }
  __syncthreads();
  const size_t obase = ((size_t)r * N_NODES + m0) * 128;
  #pragma unroll
  for (int it = 0; it < 4; ++it){
    int row = trow + it * 16;
    if (m0 + row < N_NODES){
      const float* p = Cs + row * 132 + tcol;
      ushort8 u;
      #pragma unroll
      for (int k = 0; k < 8; ++k) u[k] = f2bf(p[k]);
      *(ushort8*)(xW + obase + (size_t)row * 128 + tcol) = u;
    }
  }
}

// ---------------- K3: CSR build (3-phase scan, gidx fill) --------------------
__global__ __launch_bounds__(256) void k_scan1(const int* __restrict__ counts,
    int* __restrict__ offsets, int* __restrict__ partials){
  __shared__ int s[256];
  const int t = threadIdx.x;
  const int i = blockIdx.x * 256 + t;
  int c = (i < N_NODES) ? counts[i] : 0;
  s[t] = c;
  __syncthreads();
  for (int off = 1; off < 256; off <<= 1){
    int v = (t >= off) ? s[t - off] : 0;
    __syncthreads();
    s[t] += v;
    __syncthreads();
  }
  if (i < N_NODES) offsets[i] = s[t] - c;      // block-local exclusive prefix
  if (t == 255) partials[blockIdx.x] = s[255];
}

__global__ __launch_bounds__(128) void k_scan2(int* __restrict__ partials){
  __shared__ int s[128];
  const int t = threadIdx.x;
  int v = (t < NB_SCAN) ? partials[t] : 0;
  s[t] = v;
  __syncthreads();
  for (int off = 1; off < 128; off <<= 1){
    int u = (t >= off) ? s[t - off] : 0;
    __syncthreads();
    s[t] += u;
    __syncthreads();
  }
  if (t < NB_SCAN) partials[t] = s[t] - v;     // exclusive block base
}

__global__ __launch_bounds__(256) void k_scan3(int* __restrict__ offsets,
    int* __restrict__ cursor, const int* __restrict__ partials){
  const int i = blockIdx.x * 256 + threadIdx.x;
  if (i < N_NODES){
    int o = offsets[i] + partials[blockIdx.x];
    offsets[i] = o;
    cursor[i]  = o;
  }
  if (i == 0) offsets[N_NODES] = N_EDGES;
}

__global__ void k_fill(const int* __restrict__ dst, const int* __restrict__ src,
                       const int* __restrict__ ety, int* __restrict__ cursor,
                       int* __restrict__ gidx){
  int e = blockIdx.x * 256 + threadIdx.x;
  if (e < N_EDGES){
    int p = atomicAdd(&cursor[dst[e]], 1);
    gidx[p] = ety[e] * N_NODES + src[e];       // precomputed gather row
  }
}

// ---------------- K4: gather + segment-sum + relu (8-deep MLP) ---------------
__global__ __launch_bounds__(64) void k_agg(const int* __restrict__ offsets,
    const int* __restrict__ gidx, const u16* __restrict__ xW, float* __restrict__ out){
  const int n = blockIdx.x;
  const int t = threadIdx.x;                   // 0..63, owns channels 2t,2t+1
  const int b0 = offsets[n], b1 = offsets[n + 1];
  float2 a[8];
  #pragma unroll
  for (int j = 0; j < 8; ++j) a[j] = make_float2(0.f, 0.f);
  int e = b0;
  for (; e + 8 <= b1; e += 8){
    #pragma unroll
    for (int j = 0; j < 8; ++j){
      int g = gidx[e + j];
      u32 pk = *(const u32*)(xW + (size_t)g * 128 + t * 2);
      a[j].x += bf2f((u16)(pk & 0xffffu));
      a[j].y += bf2f((u16)(pk >> 16));
    }
  }
  for (; e < b1; ++e){
    int g = gidx[e];
    u32 pk = *(const u32*)(xW + (size_t)g * 128 + t * 2);
    a[0].x += bf2f((u16)(pk & 0xffffu));
    a[0].y += bf2f((u16)(pk >> 16));
  }
  float2 s = make_float2(0.f, 0.f);
  #pragma unroll
  for (int j = 0; j < 8; ++j){ s.x += a[j].x; s.y += a[j].y; }
  float2 o = make_float2(fmaxf(s.x, 0.f), fmaxf(s.y, 0.f));
  *(float2*)(out + (size_t)n * 128 + t * 2) = o;
}

// ---------------- launcher ---------------------------------------------------
extern "C" void kernel_launch(void* const* d_in, const int* in_sizes, int n_in,
                              void* d_out, int out_size, void* d_ws, size_t ws_size,
                              hipStream_t stream){
  const float* h      = (const float*)d_in[0];
  const float* weight = (const float*)d_in[1];
  const float* w_comp = (const float*)d_in[2];
  const int* src      = (const int*)d_in[3];
  const int* dst      = (const int*)d_in[4];
  const int* etype    = (const int*)d_in[5];
  float* out = (float*)d_out;

  char* p = (char*)d_ws;
  u16* xW      = (u16*)p;  p += 102400000;     // [20][20000][128] bf16
  u16* hb      = (u16*)p;  p += 5120000;
  u16* wrelT   = (u16*)p;  p += 655360;
  int* counts  = (int*)p;  p += 80000;
  int* offs    = (int*)p;  p += 80128;         // 20001 ints + pad
  int* cursor  = (int*)p;  p += 80000;
  int* gidx    = (int*)p;  p += 2560000;
  int* partial = (int*)p;  /* 512 B */         // total ~110.98 MB (ws >= 215 MB proven)

  hipMemsetAsync(counts, 0, N_NODES * sizeof(int), stream);
  k_cast_count<<<dim3(2500), dim3(256), 0, stream>>>(h, hb, dst, counts);
  k_wrel <<<dim3((NRELS * 128 * 128 + 255) / 256), dim3(256), 0, stream>>>(weight, w_comp, wrelT);
  k_scan1<<<dim3(NB_SCAN), dim3(256), 0, stream>>>(counts, offs, partial);
  k_scan2<<<dim3(1), dim3(128), 0, stream>>>(partial);
  k_scan3<<<dim3(NB_SCAN), dim3(256), 0, stream>>>(offs, cursor, partial);
  k_fill <<<dim3(N_EDGES / 256), dim3(256), 0, stream>>>(dst, src, etype, cursor, gidx);
  k_gemm <<<dim3(313, NRELS), dim3(256), 0, stream>>>(hb, wrelT, xW);
  k_agg  <<<dim3(N_NODES), dim3(64), 0, stream>>>(offs, gidx, xW, out);
}

// Round 5
// 201.549 us; speedup vs baseline: 2.0934x; 1.0634x over previous
//
#include <hip/hip_runtime.h>
#include <hip/hip_bf16.h>

#define N_NODES 20000
#define N_EDGES 640000
#define NRELS 20

typedef __attribute__((ext_vector_type(8))) short short8;
typedef __attribute__((ext_vector_type(8))) unsigned short ushort8;
typedef __attribute__((ext_vector_type(4))) float floatx4;
typedef unsigned short u16;
typedef unsigned int u32;

__device__ __forceinline__ float bf2f(u16 u){
  union { u32 i; float f; } v; v.i = ((u32)u) << 16; return v.f;
}
__device__ __forceinline__ u16 f2bf(float f){
  __hip_bfloat16 b = __float2bfloat16(f);
  return __builtin_bit_cast(u16, b);
}

// ---------------- K0: fused {cast h->bf16 + count + rank} | {w_rel} ----------
// blocks 0..2499: cast/count/rank (640,000 threads x4 floats)
// blocks 2500..3779: w_relT[r][o][i] (327,680 threads exactly)
__global__ __launch_bounds__(256) void k_prep(
    const float* __restrict__ h, u16* __restrict__ hb,
    const int* __restrict__ dst, int* __restrict__ counts, int* __restrict__ rank,
    const float* __restrict__ weight, const float* __restrict__ w_comp,
    u16* __restrict__ wrelT){
  const int b = blockIdx.x;
  if (b < 2500){
    int tidg = b * 256 + threadIdx.x;
    int i = tidg * 4;
    float4 v = *(const float4*)(h + i);
    u16 o[4] = { f2bf(v.x), f2bf(v.y), f2bf(v.z), f2bf(v.w) };
    *(ushort4*)(hb + i) = *(ushort4*)o;
    rank[tidg] = atomicAdd(&counts[dst[tidg]], 1);
  } else {
    int f = (b - 2500) * 256 + threadIdx.x;     // < 20*128*128 exactly
    int i  = f & 127;
    int ro = f >> 7;
    int o  = ro & 127;
    int r  = ro >> 7;
    int q  = r * 128 + i;                        // reference reshape semantics
    int rr = q % 20, ii = q / 20;
    float acc = 0.f;
    #pragma unroll
    for (int bb = 0; bb < 8; ++bb)
      acc += w_comp[rr * 8 + bb] * weight[ii * 1024 + bb * 128 + o];
    wrelT[f] = f2bf(acc);                        // [r][o][i]
  }
}

// ---------------- K1: single-block exclusive scan of counts ------------------
__global__ __launch_bounds__(1024) void k_scan(const int* __restrict__ counts,
                                               int* __restrict__ offsets){
  __shared__ int sums[1024];
  const int t = threadIdx.x;
  const int base = t * 20;                       // 1024*20 = 20480 >= 20000
  int loc[20]; int s = 0;
  #pragma unroll
  for (int j = 0; j < 20; ++j){
    int idx = base + j;
    int v = (idx < N_NODES) ? counts[idx] : 0;
    loc[j] = v; s += v;
  }
  sums[t] = s;
  __syncthreads();
  for (int off = 1; off < 1024; off <<= 1){
    int v = (t >= off) ? sums[t - off] : 0;
    __syncthreads();
    sums[t] += v;
    __syncthreads();
  }
  int run = (t == 0) ? 0 : sums[t - 1];
  #pragma unroll
  for (int j = 0; j < 20; ++j){
    int idx = base + j;
    if (idx < N_NODES){ offsets[idx] = run; run += loc[j]; }
  }
  if (t == 0) offsets[N_NODES] = N_EDGES;
}

// ---------------- K2: atomic-free CSR fill -----------------------------------
__global__ void k_fill(const int* __restrict__ dst, const int* __restrict__ src,
                       const int* __restrict__ ety, const int* __restrict__ offs,
                       const int* __restrict__ rank, int* __restrict__ gidx){
  int e = blockIdx.x * 256 + threadIdx.x;
  if (e < N_EDGES){
    int p = offs[dst[e]] + rank[e];
    gidx[p] = ety[e] * N_NODES + src[e];         // precomputed gather row
  }
}

// ---------------- K3: xW[r][n][o] = h @ W_r, RB=4 relations per block --------
#define LDP 136   // 128 + 8 pad: 272B pitch, 16B-aligned
#define RB 4

__global__ __launch_bounds__(256, 2) void k_gemm(
    const u16* __restrict__ hb, const u16* __restrict__ wrelT, u16* __restrict__ xW){
  __shared__ u16 smem[(64 + 128) * LDP];         // 52224 B
  u16* As = smem;                                // [64][136], persists all phases
  u16* Bs = smem + 64 * LDP;                     // [128][136]
  float* Cs = (float*)(smem + 64 * LDP);         // aliases Bs: 64*132*4=33792 <= 34816
  const int m0  = blockIdx.x * 64;
  const int tid = threadIdx.x;
  const int trow = tid >> 4;
  const int tcol = (tid & 15) * 8;
  const int4 zero4 = make_int4(0, 0, 0, 0);
  #pragma unroll
  for (int it = 0; it < 4; ++it){                // stage A once
    int rl = trow + it * 16;
    int gr = m0 + rl;
    int4 a = (gr < N_NODES) ? *(const int4*)(hb + (size_t)gr * 128 + tcol) : zero4;
    *(int4*)(As + rl * LDP + tcol) = a;
  }
  const int wave = tid >> 6, lane = tid & 63;
  const int lrow = lane & 15;
  const int lk   = (lane >> 4) * 8;
  for (int rb = 0; rb < RB; ++rb){
    const int r = blockIdx.y * RB + rb;
    __syncthreads();                             // A staged / prior Cs reads done
    #pragma unroll
    for (int it = 0; it < 8; ++it){              // stage B_r
      int rl = trow + it * 16;
      int4 b = *(const int4*)(wrelT + ((size_t)r * 128 + rl) * 128 + tcol);
      *(int4*)(Bs + rl * LDP + tcol) = b;
    }
    __syncthreads();
    floatx4 acc[8] = {};
    #pragma unroll
    for (int ks = 0; ks < 4; ++ks){
      short8 a0 = *(const short8*)(As + (wave * 16 + lrow) * LDP + ks * 32 + lk);
      #pragma unroll
      for (int nf = 0; nf < 8; ++nf){
        short8 b = *(const short8*)(Bs + (nf * 16 + lrow) * LDP + ks * 32 + lk);
        acc[nf] = __builtin_amdgcn_mfma_f32_16x16x32_bf16(a0, b, acc[nf], 0, 0, 0);
      }
    }
    __syncthreads();                             // Bs reads done before Cs overwrite
    #pragma unroll
    for (int nf = 0; nf < 8; ++nf)
    #pragma unroll
    for (int j = 0; j < 4; ++j){
      int row = wave * 16 + ((lane >> 4) << 2) + j;  // C/D: row=(l>>4)*4+reg
      int col = nf * 16 + (lane & 15);               //      col=l&15
      Cs[row * 132 + col] = acc[nf][j];
    }
    __syncthreads();
    const size_t obase = ((size_t)r * N_NODES + m0) * 128;
    #pragma unroll
    for (int it = 0; it < 4; ++it){
      int row = trow + it * 16;
      if (m0 + row < N_NODES){
        const float* p = Cs + row * 132 + tcol;
        ushort8 u;
        #pragma unroll
        for (int k = 0; k < 8; ++k) u[k] = f2bf(p[k]);
        *(ushort8*)(xW + obase + (size_t)row * 128 + tcol) = u;
      }
    }
  }
}

// ---------------- K4: gather + segment-sum + relu (8-deep MLP) ---------------
__global__ __launch_bounds__(64) void k_agg(const int* __restrict__ offsets,
    const int* __restrict__ gidx, const u16* __restrict__ xW, float* __restrict__ out){
  const int n = blockIdx.x;
  const int t = threadIdx.x;                     // owns channels 2t, 2t+1
  const int b0 = offsets[n], b1 = offsets[n + 1];
  float2 a[8];
  #pragma unroll
  for (int j = 0; j < 8; ++j) a[j] = make_float2(0.f, 0.f);
  int e = b0;
  for (; e + 8 <= b1; e += 8){
    #pragma unroll
    for (int j = 0; j < 8; ++j){
      int g = gidx[e + j];
      u32 pk = *(const u32*)(xW + (size_t)g * 128 + t * 2);
      a[j].x += bf2f((u16)(pk & 0xffffu));
      a[j].y += bf2f((u16)(pk >> 16));
    }
  }
  for (; e < b1; ++e){
    int g = gidx[e];
    u32 pk = *(const u32*)(xW + (size_t)g * 128 + t * 2);
    a[0].x += bf2f((u16)(pk & 0xffffu));
    a[0].y += bf2f((u16)(pk >> 16));
  }
  float2 s = make_float2(0.f, 0.f);
  #pragma unroll
  for (int j = 0; j < 8; ++j){ s.x += a[j].x; s.y += a[j].y; }
  *(float2*)(out + (size_t)n * 128 + t * 2) =
      make_float2(fmaxf(s.x, 0.f), fmaxf(s.y, 0.f));
}

// ---------------- launcher ---------------------------------------------------
extern "C" void kernel_launch(void* const* d_in, const int* in_sizes, int n_in,
                              void* d_out, int out_size, void* d_ws, size_t ws_size,
                              hipStream_t stream){
  const float* h      = (const float*)d_in[0];
  const float* weight = (const float*)d_in[1];
  const float* w_comp = (const float*)d_in[2];
  const int* src      = (const int*)d_in[3];
  const int* dst      = (const int*)d_in[4];
  const int* etype    = (const int*)d_in[5];
  float* out = (float*)d_out;

  char* p = (char*)d_ws;
  u16* xW      = (u16*)p;  p += 102400000;       // [20][20000][128] bf16
  u16* hb      = (u16*)p;  p += 5120000;
  u16* wrelT   = (u16*)p;  p += 655360;
  int* counts  = (int*)p;  p += 80000;
  int* offs    = (int*)p;  p += 80128;           // 20001 ints + pad
  int* rank    = (int*)p;  p += 2560000;
  int* gidx    = (int*)p;  /* 2,560,000 B */     // total ~113.5 MB

  hipMemsetAsync(counts, 0, N_NODES * sizeof(int), stream);
  k_prep<<<dim3(3780), dim3(256), 0, stream>>>(h, hb, dst, counts, rank,
                                               weight, w_comp, wrelT);
  k_scan<<<dim3(1), dim3(1024), 0, stream>>>(counts, offs);
  k_fill<<<dim3(N_EDGES / 256), dim3(256), 0, stream>>>(dst, src, etype, offs, rank, gidx);
  k_gemm<<<dim3(313, NRELS / RB), dim3(256), 0, stream>>>(hb, wrelT, xW);
  k_agg <<<dim3(N_NODES), dim3(64), 0, stream>>>(offs, gidx, xW, out);
}